// Round 8
// baseline (2402.625 us; speedup 1.0000x reference)
//
#include <hip/hip_runtime.h>

// SimpleRNN on MI355X — round 8: single-CU teams, PLAIN xp handoff.
// B=256, S=512, I=128, H=512, O=128; fp32 in/out, f16 MFMA internally.
//
// Diagnosis path: r4/r5/r7 (team design) all failed; the one shared
// never-validated subsystem is the fragment-permuted f16 xp handoff.
// This round removes it: xp is plain row-major f16 [s][b][j].
//  - producer: scalar f16 stores straight from the r3-proven D-mapping
//    (row b = 4g+r, col j = c) — un-mis-indexable.
//  - consumer: 32 scalar f16 loads per lane per step, issued at step top,
//    consumed after the MFMA phase (latency hidden); acc starts at 0 and
//    xp (bias folded) is added just before tanh.
// Everything else identical to r7: W_hh kt=0..12 register-resident
// (416 VGPRs, proven formula), kt=13..15 in LDS [512][104]; h exchanged
// via single 16KB swizzled LDS buffer (proven swizzle pair); 2 barriers
// per step; LDS total 122,880 B (< r2's proven 131,072).

#define B_SZ 256
#define S_SZ 512
#define I_SZ 128
#define H_SZ 512
#define O_SZ 128

typedef _Float16 f16;
typedef _Float16 f16x8 __attribute__((ext_vector_type(8)));
typedef _Float16 f16x2 __attribute__((ext_vector_type(2)));
typedef float f32x4 __attribute__((ext_vector_type(4)));

__device__ __forceinline__ f16x8 cvt8(float4 a, float4 b) {
    f16x8 r;
    f16x2 p;
    p = __builtin_bit_cast(f16x2, __builtin_amdgcn_cvt_pkrtz(a.x, a.y)); r[0] = p[0]; r[1] = p[1];
    p = __builtin_bit_cast(f16x2, __builtin_amdgcn_cvt_pkrtz(a.z, a.w)); r[2] = p[0]; r[3] = p[1];
    p = __builtin_bit_cast(f16x2, __builtin_amdgcn_cvt_pkrtz(b.x, b.y)); r[4] = p[0]; r[5] = p[1];
    p = __builtin_bit_cast(f16x2, __builtin_amdgcn_cvt_pkrtz(b.z, b.w)); r[6] = p[0]; r[7] = p[1];
    return r;
}

// xp[(s*256 + b)*512 + j] = x_s[b] . Wih[j] + bih[j] + bhh[j], f16, plain.
__global__ __launch_bounds__(256) void xp_prepass2(
    const float* __restrict__ x, const float* __restrict__ Wih,
    const float* __restrict__ bih, const float* __restrict__ bhh,
    f16* __restrict__ xp)
{
    const int s = blockIdx.x;
    const int tid = threadIdx.x, w = tid >> 6, lane = tid & 63;
    const int c = lane & 15, g = lane >> 4;

    // Wih B-fragments (round-3 proven formula): j = w*128+nt*16+c
    f16x8 wxb[8][4];
#pragma unroll
    for (int nt = 0; nt < 8; ++nt)
#pragma unroll
        for (int kx = 0; kx < 4; ++kx) {
            const float* src = Wih + (size_t)(w * 128 + nt * 16 + c) * I_SZ + kx * 32 + g * 8;
            wxb[nt][kx] = cvt8(*(const float4*)src, *(const float4*)(src + 4));
        }
    float bs[8];
#pragma unroll
    for (int nt = 0; nt < 8; ++nt)
        bs[nt] = bih[w * 128 + nt * 16 + c] + bhh[w * 128 + nt * 16 + c];

    for (int team = 0; team < 16; ++team) {
        // x A-fragments (round-3 proven formula): b = team*16 + c
        f16x8 ax[4];
#pragma unroll
        for (int kx = 0; kx < 4; ++kx) {
            const float* src = x + ((size_t)(team * 16 + c) * S_SZ + s) * I_SZ + kx * 32 + g * 8;
            ax[kx] = cvt8(*(const float4*)src, *(const float4*)(src + 4));
        }
        f32x4 acc[8];
#pragma unroll
        for (int nt = 0; nt < 8; ++nt) acc[nt] = (f32x4){0.f, 0.f, 0.f, 0.f};
#pragma unroll
        for (int kx = 0; kx < 4; ++kx)
#pragma unroll
            for (int nt = 0; nt < 8; ++nt)
                acc[nt] = __builtin_amdgcn_mfma_f32_16x16x32_f16(ax[kx], wxb[nt][kx], acc[nt], 0, 0, 0);

        // D mapping (proven): row b = team*16 + 4g + r, col j = w*128+nt*16+c.
        // Plain scalar stores — no permutation, no packing.
        f16* dst = xp + ((size_t)s * B_SZ + (size_t)team * 16) * H_SZ;
#pragma unroll
        for (int nt = 0; nt < 8; ++nt) {
            int col = w * 128 + nt * 16 + c;
#pragma unroll
            for (int r = 0; r < 4; ++r)
                dst[(size_t)(g * 4 + r) * H_SZ + col] = (f16)(acc[nt][r] + bs[nt]);
        }
    }
}

// rnn_team3: one WG per 16 batch rows. LDS total 122,880 B.
__global__ __launch_bounds__(256, 1) void rnn_team3(
    const float* __restrict__ Whh, const f16* __restrict__ xp,
    f16* __restrict__ hout)
{
    __shared__ f16 wlds[512 * 104];   // 106,496 B : W_hh[j][k=416..511]
    __shared__ f16 hst[16 * 512];     //  16,384 B : h, single buffer, swizzled

    const int team = blockIdx.x;
    const int tid = threadIdx.x, w = tid >> 6, lane = tid & 63;
    const int c = lane & 15, g = lane >> 4;
    const int bt = team * 16;

    // stage W_hh k=416..511 (row stride 104 f16 = 208 B)
    for (int rr = 0; rr < 2; ++rr) {
        int row = tid * 2 + rr;
        const float* src = Whh + (size_t)row * H_SZ + 416;
#pragma unroll
        for (int i = 0; i < 96; i += 8)
            *(f16x8*)(wlds + row * 104 + i) =
                cvt8(*(const float4*)(src + i), *(const float4*)(src + i + 4));
    }

    // W_hh B-fragments kt=0..12, register resident (round-3 proven formula)
    f16x8 wb[8][13];
#pragma unroll
    for (int nt = 0; nt < 8; ++nt)
#pragma unroll
        for (int kt = 0; kt < 13; ++kt) {
            const float* src = Whh + (size_t)(w * 128 + nt * 16 + c) * H_SZ + kt * 32 + g * 8;
            wb[nt][kt] = cvt8(*(const float4*)src, *(const float4*)(src + 4));
        }
    __syncthreads();

    for (int s = 0; s < S_SZ; ++s) {
        // xp for this step: 32 scalar f16 loads from the PLAIN layout.
        // Issued here, consumed after the MFMA phase (latency hidden).
        const f16* xs = xp + ((size_t)s * B_SZ + bt) * H_SZ;
        float xv[8][4];
#pragma unroll
        for (int nt = 0; nt < 8; ++nt)
#pragma unroll
            for (int r = 0; r < 4; ++r)
                xv[nt][r] = (float)xs[(size_t)(g * 4 + r) * H_SZ + w * 128 + nt * 16 + c];

        f32x4 acc[8];
#pragma unroll
        for (int nt = 0; nt < 8; ++nt) acc[nt] = (f32x4){0.f, 0.f, 0.f, 0.f};

        if (s > 0) {
#pragma unroll
            for (int kt = 0; kt < 13; ++kt) {
                // round-3 proven A-frag read: h[b=c][k=kt*32+g*8+e]
                f16x8 ah = *(const f16x8*)(hst + c * 512 + ((kt * 4 + g) ^ (c & 7)) * 8);
#pragma unroll
                for (int nt = 0; nt < 8; ++nt)
                    acc[nt] = __builtin_amdgcn_mfma_f32_16x16x32_f16(ah, wb[nt][kt], acc[nt], 0, 0, 0);
            }
#pragma unroll
            for (int kt = 13; kt < 16; ++kt) {
                f16x8 ah = *(const f16x8*)(hst + c * 512 + ((kt * 4 + g) ^ (c & 7)) * 8);
#pragma unroll
                for (int nt = 0; nt < 8; ++nt) {
                    f16x8 wv = *(const f16x8*)(wlds + (w * 128 + nt * 16 + c) * 104
                                               + (kt - 13) * 32 + g * 8);
                    acc[nt] = __builtin_amdgcn_mfma_f32_16x16x32_f16(ah, wv, acc[nt], 0, 0, 0);
                }
            }
        }
        __syncthreads();   // all hst reads of h(s) complete

        // tanh(acc + xp) -> round-3 proven writer: row=4g+r, col^((row&7)<<3)
#pragma unroll
        for (int nt = 0; nt < 8; ++nt) {
            int col = w * 128 + nt * 16 + c;
#pragma unroll
            for (int r = 0; r < 4; ++r) {
                float pre = acc[nt][r] + xv[nt][r];
                float e = __expf(2.f * pre);
                float hv = 1.f - 2.f * __builtin_amdgcn_rcpf(e + 1.f);
                int row = g * 4 + r;
                hst[row * 512 + (col ^ ((row & 7) << 3))] = (f16)hv;
                if (s == S_SZ - 1)
                    hout[(size_t)(bt + row) * H_SZ + col] = (f16)hv;
            }
        }
        __syncthreads();   // h(s+1) visible for next step
    }
}

// out[b][o] = sum_k h[b][k] * Wfc[o][k] + bfc[o]
__global__ __launch_bounds__(128) void fc_kernel(
    const f16* __restrict__ hbuf, const float* __restrict__ Wfc,
    const float* __restrict__ bfc, float* __restrict__ out)
{
    __shared__ float hs[H_SZ];
    int b = blockIdx.x, o = threadIdx.x;
    for (int k = o; k < H_SZ; k += 128)
        hs[k] = (float)hbuf[(size_t)b * H_SZ + k];
    __syncthreads();
    const float* wr = Wfc + (size_t)o * H_SZ;
    float acc = bfc[o];
#pragma unroll 8
    for (int k = 0; k < H_SZ; k += 4) {
        float4 wv = *(const float4*)(wr + k);
        acc += wv.x * hs[k] + wv.y * hs[k + 1] + wv.z * hs[k + 2] + wv.w * hs[k + 3];
    }
    out[(size_t)b * O_SZ + o] = acc;
}

extern "C" void kernel_launch(void* const* d_in, const int* in_sizes, int n_in,
                              void* d_out, int out_size, void* d_ws, size_t ws_size,
                              hipStream_t stream) {
    const float* x   = (const float*)d_in[0];
    const float* Wih = (const float*)d_in[1];
    const float* Whh = (const float*)d_in[2];
    const float* bih = (const float*)d_in[3];
    const float* bhh = (const float*)d_in[4];
    const float* Wfc = (const float*)d_in[5];
    const float* bfc = (const float*)d_in[6];
    float* out = (float*)d_out;

    // ws layout: hout (256 KB) at 0; xp plain f16 [s][b][j] (128 MiB) at 1 MiB.
    // ws_size >= 129 MiB established (r4/r5 selected this path via guard).
    f16* hout = (f16*)d_ws;
    f16* xp   = (f16*)((char*)d_ws + ((size_t)1 << 20));

    hipLaunchKernelGGL(xp_prepass2, dim3(S_SZ), dim3(256), 0, stream,
                       x, Wih, bih, bhh, xp);
    hipLaunchKernelGGL(rnn_team3, dim3(16), dim3(256), 0, stream,
                       Whh, xp, hout);
    hipLaunchKernelGGL(fc_kernel, dim3(B_SZ), dim3(128), 0, stream,
                       hout, Wfc, bfc, out);
}